// Round 9
// baseline (125.887 us; speedup 1.0000x reference)
//
#include <hip/hip_runtime.h>

// ---------------------------------------------------------------------------
// AMM chain, round 9: R7 skeleton, chain kernels rebuilt for TLP.
//   D1 conv | D2 {Q, C1:[q|betas2], W0} 1536 blk | D3 W0' 512 blk |
//   D4 {z0(soft) || ypart=betas2@V1^T} 2048 blk | D5-7 ZQ 1024 blk |
//   D8 ZQF(out=ypart+soft(...)) 1024 blk
// gtile: 64x64, 4 waves (2M x 2K), 3-buf ahead-1, 48KB, vmcnt(4/0).
// gt32k: 32x32, BK=128, 4 waves (pure 4K split), 3-buf ahead-1, 48KB,
//        16-chunk XOR swizzle, 4-way LDS reduction, vmcnt(4/0).
// Math identical to R7 (projector fold, diag-exact Q).
// ---------------------------------------------------------------------------

typedef _Float16 f16x8 __attribute__((ext_vector_type(8)));
typedef _Float16 f16x4 __attribute__((ext_vector_type(4)));
typedef float f32x4 __attribute__((ext_vector_type(4)));

enum { EPI_H, EPI_QOFF, EPI_SPLIT };              // gtile epilogues
enum { CEPI_SOFT, CEPI_YP, CEPI_ZQ, CEPI_ZQFO };  // chain epilogues

typedef const __attribute__((address_space(1))) void* gas_ptr;
typedef __attribute__((address_space(3))) void* las_ptr;

__device__ __forceinline__ void gload16(const void* g, void* l) {
  __builtin_amdgcn_global_load_lds((gas_ptr)g, (las_ptr)l, 16, 0, 0);
}

__device__ __forceinline__ float softt(float t) {
  float s = fabsf(t) - 1.0f;
  s = s > 0.0f ? s : 0.0f;
  return copysignf(s, t);
}

// ---------------------------------------------------------------------------
// unified conversion kernel (R7-proven). block (32,8).
// z=0..3 transposing f32->f16 (optional scale); z=4 plain f32->f16 x3.
// ---------------------------------------------------------------------------
__global__ __launch_bounds__(256) void convAll(
    const float* __restrict__ e0, const float* __restrict__ e1,
    const float* __restrict__ e2, const float* __restrict__ e3,
    _Float16* __restrict__ o0, _Float16* __restrict__ o1,
    _Float16* __restrict__ o2, _Float16* __restrict__ o3,
    const float* __restrict__ s1, const float* __restrict__ s2,
    const float4* __restrict__ pa, f16x4* __restrict__ qa, int na,
    const float4* __restrict__ pb, f16x4* __restrict__ qb, int nb,
    const float4* __restrict__ pc, f16x4* __restrict__ qc, int nc) {
  const int z = blockIdx.z;
  if (z == 4) {
    const int total = na + nb + nc;
    const int bid = blockIdx.y * 32 + blockIdx.x;
    const int nthr = 2048 * 256;
    for (int i = bid * 256 + threadIdx.y * 32 + threadIdx.x; i < total;
         i += nthr) {
      const float4* s;
      f16x4* d;
      int j = i;
      if (j < na) {
        s = pa; d = qa;
      } else if ((j -= na) < nb) {
        s = pb; d = qb;
      } else {
        j -= nb; s = pc; d = qc;
      }
      float4 v = s[j];
      f16x4 h = {(_Float16)v.x, (_Float16)v.y, (_Float16)v.z, (_Float16)v.w};
      d[j] = h;
    }
    return;
  }
  const float* in = z == 0 ? e0 : z == 1 ? e1 : z == 2 ? e2 : e3;
  _Float16* out = z == 0 ? o0 : z == 1 ? o1 : z == 2 ? o2 : o3;
  const int R = (z < 2) ? 2048 : 1024;
  const int C = 1024;
  const int mode = z == 1 ? 1 : z == 2 ? 2 : 0;
  const float* sv = z == 1 ? s1 : s2;
  __shared__ float t[32][33];
  const int tx = threadIdx.x, ty = threadIdx.y;
  const int c0 = blockIdx.x * 32, r0 = blockIdx.y * 32;
  if (r0 >= R) return;  // uniform per block
#pragma unroll
  for (int i = 0; i < 32; i += 8)
    t[ty + i][tx] = in[(size_t)(r0 + ty + i) * C + c0 + tx];
  __syncthreads();
#pragma unroll
  for (int i = 0; i < 32; i += 8) {
    float v = t[tx][ty + i];
    if (mode == 1) v *= sv[c0 + ty + i];
    if (mode == 2) v *= sv[r0 + tx];
    out[(size_t)(c0 + ty + i) * R + r0 + tx] = (_Float16)v;
  }
}

// ---------------------------------------------------------------------------
// 64x64 tile, NT, 4 waves (wr=M-half, wk=K-half), wave tile 32x64.
// 3 LDS bufs, stage-ahead 1, vmcnt(4/0), 1 barrier/K-step. 48KB.
// Safety: write buf (kt+1)%3 at step kt; last read at step kt-2; barrier(kt-1)
// separates (all waves passed it only after completing step kt-2 reads).
// ---------------------------------------------------------------------------
template <int EPI>
__device__ __forceinline__ void gtile(
    const _Float16* __restrict__ A, int lda, const _Float16* __restrict__ B,
    int ldb, int nK, int N, int brow, int bcol, float* __restrict__ dgout,
    _Float16* __restrict__ oh, _Float16* __restrict__ oh2, _Float16* sm,
    int tid) {
  const int lane = tid & 63;
  const int w = tid >> 6;
  const int wr = w & 1;
  const int wk = w >> 1;
  const int srow = lane >> 3;
  const int scol = ((lane & 7) ^ srow) << 3;
  const int a15 = lane & 15;
  const int hi = lane >> 4;
  const int l7 = lane & 7;

  const _Float16* apg = A + (size_t)(brow + (w << 4) + srow) * lda + scol;
  const _Float16* bpg = B + (size_t)(bcol + (w << 4) + srow) * ldb + scol;
  _Float16* AB = sm;            // 3 x 4096 halfs
  _Float16* BB = sm + 12288;    // 3 x 4096 halfs
  const int ldstA = w << 10;

  const int ca = ((wk << 2) + hi) ^ l7;
  int raddr[2], baddr[4];
#pragma unroll
  for (int mi = 0; mi < 2; ++mi)
    raddr[mi] = ((wr << 5) + (mi << 4) + a15) * 64 + (ca << 3);
#pragma unroll
  for (int ni = 0; ni < 4; ++ni)
    baddr[ni] = ((ni << 4) + a15) * 64 + (ca << 3);

  f32x4 acc[2][4] = {};
  __syncthreads();

  // prologue: buf 0
  gload16(apg, AB + ldstA);
  gload16(apg + (size_t)8 * lda, AB + ldstA + 512);
  gload16(bpg, BB + ldstA);
  gload16(bpg + (size_t)8 * ldb, BB + ldstA + 512);

  int bi = 0, bs = 1;
  for (int kt = 0; kt < nK; ++kt) {
    if (kt + 1 < nK) {
      const int co = (kt + 1) << 6;
      gload16(apg + co, AB + bs * 4096 + ldstA);
      gload16(apg + co + (size_t)8 * lda, AB + bs * 4096 + ldstA + 512);
      gload16(bpg + co, BB + bs * 4096 + ldstA);
      gload16(bpg + co + (size_t)8 * ldb, BB + bs * 4096 + ldstA + 512);
      asm volatile("s_waitcnt vmcnt(4)" ::: "memory");
    } else {
      asm volatile("s_waitcnt vmcnt(0)" ::: "memory");
    }
    __builtin_amdgcn_s_barrier();
    __builtin_amdgcn_sched_barrier(0);
    const _Float16* Ab = AB + bi * 4096;
    const _Float16* Bb = BB + bi * 4096;
    f16x8 av[2], bv[4];
    av[0] = *(const f16x8*)(Ab + raddr[0]);
    av[1] = *(const f16x8*)(Ab + raddr[1]);
    bv[0] = *(const f16x8*)(Bb + baddr[0]);
    bv[1] = *(const f16x8*)(Bb + baddr[1]);
    bv[2] = *(const f16x8*)(Bb + baddr[2]);
    bv[3] = *(const f16x8*)(Bb + baddr[3]);
#pragma unroll
    for (int mi = 0; mi < 2; ++mi)
#pragma unroll
      for (int ni = 0; ni < 4; ++ni)
        acc[mi][ni] = __builtin_amdgcn_mfma_f32_16x16x32_f16(
            av[mi], bv[ni], acc[mi][ni], 0, 0, 0);
    bi = bi == 2 ? 0 : bi + 1;
    bs = bs == 2 ? 0 : bs + 1;
  }

  __syncthreads();
  float* scr = (float*)sm;
  const int sl = (wr << 6) + lane;
  if (wk == 1) {
#pragma unroll
    for (int mi = 0; mi < 2; ++mi)
#pragma unroll
      for (int ni = 0; ni < 4; ++ni)
#pragma unroll
        for (int r = 0; r < 4; ++r)
          scr[(((mi << 2) + ni) * 4 + r) * 128 + sl] = acc[mi][ni][r];
  }
  __syncthreads();
  if (wk == 0) {
#pragma unroll
    for (int mi = 0; mi < 2; ++mi) {
#pragma unroll
      for (int ni = 0; ni < 4; ++ni) {
#pragma unroll
        for (int r = 0; r < 4; ++r) {
          const float v =
              acc[mi][ni][r] + scr[(((mi << 2) + ni) * 4 + r) * 128 + sl];
          const int row = brow + (wr << 5) + (mi << 4) + (hi << 2) + r;
          const int col = bcol + (ni << 4) + a15;
          const size_t idx = (size_t)row * N + col;
          if constexpr (EPI == EPI_H) {
            oh[idx] = (_Float16)v;
          } else if constexpr (EPI == EPI_QOFF) {
            if (row == col) {
              dgout[row] = 1.0f - v;
              oh[idx] = (_Float16)0.0f;
            } else {
              oh[idx] = (_Float16)(-v);
            }
          } else {  // EPI_SPLIT
            if (col < 1024)
              oh[(size_t)row * 1024 + col] = (_Float16)v;
            else
              oh2[(size_t)row * 1024 + (col - 1024)] = (_Float16)v;
          }
        }
      }
    }
  }
}

// ---------------------------------------------------------------------------
// chain kernel tile: 32x32 output, BK=128, 4 waves = pure K-split (wave w
// owns k-window [w*32, w*32+32) of each 128-step). 3 bufs x (A 8KB + B 8KB)
// = 48KB, stage-ahead 1, vmcnt(4/0), 1 barrier/step.
// LDS layout: row r (0..31), 16 chunks of 8 halfs; chunk c stored at
// c ^ (r&15) (staged linearly; source col pre-swizzled). Read: kchunk
// (w*4+hi) ^ a15. 4-way f32 LDS reduction; wave 0 does the epilogue.
// ---------------------------------------------------------------------------
template <int EPI>
__device__ __forceinline__ void gt32k(
    const _Float16* __restrict__ A, int lda, const _Float16* __restrict__ B,
    int ldb, int nK, int brow, int bcol, const float* __restrict__ dgv,
    float* __restrict__ z0f, float* __restrict__ zff, float* __restrict__ yp,
    _Float16* __restrict__ oh, float* __restrict__ ofin, _Float16* sm,
    int tid) {
  const int lane = tid & 63;
  const int w = tid >> 6;  // K-quarter 0..3
  const int a15 = lane & 15;
  const int hi = lane >> 4;

  // staging: 2 A-chunks + 2 B-chunks per thread. instr1: chunk li=tid
  // (row=li>>4 in 0..15), instr2: +256 chunks (row+16, same swizzled col).
  const int row1 = tid >> 4;          // 0..15
  const int clin = tid & 15;
  const int scol = (clin ^ row1) << 3;  // pre-swizzled source col (halfs)
  const _Float16* apg = A + (size_t)(brow + row1) * lda + scol;
  const _Float16* bpg = B + (size_t)(bcol + row1) * ldb + scol;
  _Float16* AB = sm;            // 3 x 4096 halfs
  _Float16* BB = sm + 12288;    // 3 x 4096 halfs
  const int dst = w << 9;       // wave-uniform chunk base (halfs)

  const int ro = ((w << 2) + hi) ^ a15;  // swizzled k-chunk for frag reads
  const int raddr0 = a15 * 128 + (ro << 3);
  const int raddr1 = (16 + a15) * 128 + (ro << 3);
  const int baddr0 = raddr0;
  const int baddr1 = raddr1;

  f32x4 acc[2][2] = {};
  __syncthreads();

  // prologue: buf 0 (k-step 0)
  gload16(apg, AB + dst);
  gload16(apg + (size_t)16 * lda, AB + dst + 2048);
  gload16(bpg, BB + dst);
  gload16(bpg + (size_t)16 * ldb, BB + dst + 2048);

  int bi = 0, bs = 1;
  for (int kt = 0; kt < nK; ++kt) {
    if (kt + 1 < nK) {
      const int co = (kt + 1) << 7;  // 128 halfs per K-step
      gload16(apg + co, AB + bs * 4096 + dst);
      gload16(apg + co + (size_t)16 * lda, AB + bs * 4096 + dst + 2048);
      gload16(bpg + co, BB + bs * 4096 + dst);
      gload16(bpg + co + (size_t)16 * ldb, BB + bs * 4096 + dst + 2048);
      asm volatile("s_waitcnt vmcnt(4)" ::: "memory");
    } else {
      asm volatile("s_waitcnt vmcnt(0)" ::: "memory");
    }
    __builtin_amdgcn_s_barrier();
    __builtin_amdgcn_sched_barrier(0);
    const _Float16* Ab = AB + bi * 4096;
    const _Float16* Bb = BB + bi * 4096;
    f16x8 av0 = *(const f16x8*)(Ab + raddr0);
    f16x8 av1 = *(const f16x8*)(Ab + raddr1);
    f16x8 bv0 = *(const f16x8*)(Bb + baddr0);
    f16x8 bv1 = *(const f16x8*)(Bb + baddr1);
    acc[0][0] =
        __builtin_amdgcn_mfma_f32_16x16x32_f16(av0, bv0, acc[0][0], 0, 0, 0);
    acc[0][1] =
        __builtin_amdgcn_mfma_f32_16x16x32_f16(av0, bv1, acc[0][1], 0, 0, 0);
    acc[1][0] =
        __builtin_amdgcn_mfma_f32_16x16x32_f16(av1, bv0, acc[1][0], 0, 0, 0);
    acc[1][1] =
        __builtin_amdgcn_mfma_f32_16x16x32_f16(av1, bv1, acc[1][1], 0, 0, 0);
    bi = bi == 2 ? 0 : bi + 1;
    bs = bs == 2 ? 0 : bs + 1;
  }

  // 4-way K reduction through LDS (12KB, conflict-free: lane-consecutive)
  __syncthreads();
  float* scr = (float*)sm;
  if (w) {
#pragma unroll
    for (int mi = 0; mi < 2; ++mi)
#pragma unroll
      for (int ni = 0; ni < 2; ++ni)
#pragma unroll
        for (int r = 0; r < 4; ++r)
          scr[((((w - 1) << 2) + (mi << 1) + ni) * 4 + r) * 64 + lane] =
              acc[mi][ni][r];
  }
  __syncthreads();
  if (w != 0) return;
#pragma unroll
  for (int mi = 0; mi < 2; ++mi) {
#pragma unroll
    for (int ni = 0; ni < 2; ++ni) {
#pragma unroll
      for (int j = 0; j < 3; ++j)
#pragma unroll
        for (int r = 0; r < 4; ++r)
          acc[mi][ni][r] +=
              scr[(((j << 2) + (mi << 1) + ni) * 4 + r) * 64 + lane];
#pragma unroll
      for (int r = 0; r < 4; ++r) {
        const int row = brow + (mi << 4) + (hi << 2) + r;
        const int col = bcol + (ni << 4) + a15;
        const float v = acc[mi][ni][r];
        const size_t idx = (size_t)row * 2048 + col;
        if constexpr (EPI == CEPI_SOFT) {
          z0f[idx] = v;
          float s = softt(v);
          zff[idx] = s;
          oh[idx] = (_Float16)s;
        } else if constexpr (EPI == CEPI_YP) {
          yp[idx] = v;
        } else if constexpr (EPI == CEPI_ZQ) {
          float t = z0f[idx] + dgv[col] * zff[idx] + v;
          float s = softt(t);
          zff[idx] = s;
          oh[idx] = (_Float16)s;
        } else {  // CEPI_ZQFO
          float t = z0f[idx] + dgv[col] * zff[idx] + v;
          ofin[idx] = yp[idx] + softt(t);
        }
      }
    }
  }
}

// ---------------------------------------------------------------------------
struct WS {
  const _Float16 *ve, *vt1, *w0pT_r, *Bcat, *qoff_r, *x, *kt0s, *vt0T, *w0_r,
      *q_r, *be2;
  _Float16 *w0pT_w, *qoff_w, *w0_w, *q_w, *be2_w, *zhA, *zhB;
  float *z0, *zf, *dg, *yp;
};

// XCD-chunked map for 16(brow32) x 64(bcol32) chain grids (1024 blocks)
__device__ __forceinline__ void mapc(int b, int& br, int& bc) {
  const int x = b & 7, i = b >> 3;
  bc = (x << 3) | (i & 7);  // 0..63
  br = i >> 3;              // 0..15
}

__global__ __launch_bounds__(256, 3) void kD2(WS p) {
  __shared__ __align__(16) _Float16 sm[24576];
  const int tid = threadIdx.x;
  const int bid = blockIdx.x;
  if (bid < 1024) {  // Q = I - Ve Ve^T (2048x2048, K=1024)
    gtile<EPI_QOFF>(p.ve, 1024, p.ve, 1024, 16, 2048, (bid >> 5) << 6,
                    (bid & 31) << 6, p.dg, p.qoff_w, nullptr, sm, tid);
  } else if (bid < 1280) {  // C1: [q|betas2] = x @ Bcat (512x2048, K=2048)
    const int i = bid - 1024;
    gtile<EPI_SPLIT>(p.x, 2048, p.Bcat, 2048, 32, 2048, (i >> 5) << 6,
                     (i & 31) << 6, nullptr, p.q_w, p.be2_w, sm, tid);
  } else {  // W0 = (K0^T s0) @ V0 (1024x1024, K=1024)
    const int i = bid - 1280;
    gtile<EPI_H>(p.kt0s, 1024, p.vt0T, 1024, 16, 1024, (i >> 4) << 6,
                 (i & 15) << 6, nullptr, p.w0_w, nullptr, sm, tid);
  }
}

__global__ __launch_bounds__(256, 3) void kW0p(WS p) {
  __shared__ __align__(16) _Float16 sm[24576];
  const int x = blockIdx.x & 7, i = blockIdx.x >> 3;
  const int bc = (x << 1) | (i & 1), br = i >> 1;  // 16 bcol x 32 brow
  gtile<EPI_H>(p.ve, 1024, p.w0_r, 1024, 16, 1024, br << 6, bc << 6, nullptr,
               p.w0pT_w, nullptr, sm, threadIdx.x);
}

// D4: blocks 0..1023 -> z0 = q @ W0' (soft); 1024..2047 -> ypart = be2 @ V1^T
__global__ __launch_bounds__(256, 3) void kD4(WS p) {
  __shared__ __align__(16) _Float16 sm[24576];
  const int bid = blockIdx.x;
  int br, bc;
  if (bid < 1024) {
    mapc(bid, br, bc);
    gt32k<CEPI_SOFT>(p.q_r, 1024, p.w0pT_r, 1024, 8, br << 5, bc << 5,
                     nullptr, p.z0, p.zf, nullptr, p.zhA, nullptr, sm,
                     threadIdx.x);
  } else {
    mapc(bid - 1024, br, bc);
    gt32k<CEPI_YP>(p.be2, 1024, p.vt1, 1024, 8, br << 5, bc << 5, nullptr,
                   nullptr, nullptr, p.yp, nullptr, nullptr, sm, threadIdx.x);
  }
}

template <bool AB>
__global__ __launch_bounds__(256, 3) void kZQ(WS p) {
  __shared__ __align__(16) _Float16 sm[24576];
  int br, bc;
  mapc(blockIdx.x, br, bc);  // z = soft(z0 + dg*z + z@Qoff)
  gt32k<CEPI_ZQ>(AB ? p.zhA : p.zhB, 2048, p.qoff_r, 2048, 16, br << 5,
                 bc << 5, p.dg, p.z0, p.zf, nullptr, AB ? p.zhB : p.zhA,
                 nullptr, sm, threadIdx.x);
}

__global__ __launch_bounds__(256, 3) void kZQF(WS p, float* out) {
  __shared__ __align__(16) _Float16 sm[24576];
  int br, bc;
  mapc(blockIdx.x, br, bc);  // out = ypart + soft(z0 + dg*z + z@Qoff)
  gt32k<CEPI_ZQFO>(p.zhB, 2048, p.qoff_r, 2048, 16, br << 5, bc << 5, p.dg,
                   p.z0, p.zf, p.yp, nullptr, out, sm, threadIdx.x);
}

// ---------------------------------------------------------------------------
extern "C" void kernel_launch(void* const* d_in, const int* in_sizes, int n_in,
                              void* d_out, int out_size, void* d_ws,
                              size_t ws_size, hipStream_t stream) {
  const float* x = (const float*)d_in[0];          // (512,2048)
  const float* key_enc = (const float*)d_in[1];    // (2048,1024)
  const float* val_enc = (const float*)d_in[2];    // (2048,1024)
  const float* keys_t0 = (const float*)d_in[3];    // (1024,1024)
  const float* vals_t0 = (const float*)d_in[4];    // (1024,1024)
  const float* scales_t0 = (const float*)d_in[5];  // (1024,)
  const float* keys_t1 = (const float*)d_in[6];    // (2048,1024)
  const float* vals_t1 = (const float*)d_in[7];    // (2048,1024)
  const float* scales_t1 = (const float*)d_in[8];  // (1024,)

  // workspace (half offsets; 1M = 1048576), lifetime-overlaid, ~44 MB
  constexpr size_t M1 = 1048576;
  _Float16* ws = (_Float16*)d_ws;
  _Float16* ve_h = ws;                    // [0,2M)   Ve f16 (reads D2,D3)
  _Float16* vt1_h = ws + 2 * M1;          // [2M,4M)  vals_t1 (D4 ypart)
  _Float16* w0pT = ws + 4 * M1;           // [4M,6M)  W0' (D3 out, D4 B)
  _Float16* Bcat = ws + 6 * M1;           // [6M,10M) conv out, D2-C1 B
  _Float16* zhA = ws + 6 * M1;            //   overlay (post-D2)
  float* z0_f = (float*)(ws + 7 * M1);    //   overlay (post-D2): 2M halfs
  _Float16* zhB = ws + 9 * M1;            //   overlay (post-D2)
  _Float16* qoff = ws + 10 * M1;          // [10M,14M) Q off-diag (D2 out)
  _Float16* x_h = ws + 14 * M1;           // [14M,15M) conv; D2-C1 A
  _Float16* kt0s = ws + 15 * M1;          // [15M,16M) conv; D2-W0 A
  float* z_f = (float*)(ws + 15 * M1);    //   overlay (post-D2): 2M halfs
  _Float16* vt0T = ws + 16 * M1;          // [16M,17M) conv; D2-W0 B
  _Float16* w0 = ws + 17 * M1;            // [17M,18M) D2-W0 out, D3 B
  _Float16* q_h = ws + 18 * M1;           // [18M,18.5M)
  _Float16* be2 = ws + 18 * M1 + 524288;  // [18.5M,19M)
  float* dg = (float*)(ws + 19 * M1);     // [19M,+8KB) D2 out
  float* yp = (float*)(ws + 20 * M1);     // [20M,22M) D4 out, D8 in

  WS p;
  p.ve = ve_h; p.vt1 = vt1_h; p.w0pT_r = w0pT; p.w0pT_w = w0pT;
  p.Bcat = Bcat; p.qoff_r = qoff; p.qoff_w = qoff; p.x = x_h;
  p.kt0s = kt0s; p.vt0T = vt0T; p.w0_r = w0; p.w0_w = w0;
  p.q_r = q_h; p.q_w = q_h; p.be2 = be2; p.be2_w = be2;
  p.zhA = zhA; p.zhB = zhB; p.z0 = z0_f; p.zf = z_f; p.dg = dg; p.yp = yp;

  // D1: conversions
  convAll<<<dim3(32, 64, 5), dim3(32, 8), 0, stream>>>(
      key_enc, keys_t1, keys_t0, vals_t0, Bcat, Bcat + 2 * M1, kt0s, vt0T,
      scales_t1, scales_t0, (const float4*)x, (f16x4*)x_h, 262144,
      (const float4*)val_enc, (f16x4*)ve_h, 524288, (const float4*)vals_t1,
      (f16x4*)vt1_h, 524288);
  // D2: Q || C1 || W0
  kD2<<<1536, 256, 0, stream>>>(p);
  // D3: W0' = Ve @ W0^T
  kW0p<<<512, 256, 0, stream>>>(p);
  // D4: z0 = q @ W0' (soft) || ypart = betas2 @ V1^T
  kD4<<<2048, 256, 0, stream>>>(p);
  // D5-D7: ISTA iters 2..4 (zh ping-pong)
  kZQ<true><<<1024, 256, 0, stream>>>(p);   // zhA -> zhB
  kZQ<false><<<1024, 256, 0, stream>>>(p);  // zhB -> zhA
  kZQ<true><<<1024, 256, 0, stream>>>(p);   // zhA -> zhB
  // D8: ISTA iter 5 + out = ypart + soft(...)
  kZQF<<<1024, 256, 0, stream>>>(p, (float*)d_out);
}

// Round 10
// 110.091 us; speedup vs baseline: 1.1435x; 1.1435x over previous
//
#include <hip/hip_runtime.h>

// ---------------------------------------------------------------------------
// AMM chain, round 10: R7 structure (proven 110 µs) + final-GEMM hoisted into
// D4 (runs parallel with z0), leaving D8 as a single fused ZQ+output kernel.
//   D1 conv | D2 {Q, C1:[q|betas2], W0} 1536 blk | D3 W0' 512 blk |
//   D4 {z0(soft) || ypart=betas2@V1^T} 1024 blk | D5-7 ZQ 512 blk |
//   D8 out = ypart + soft(z0 + dg*z + z@Qoff) 512 blk
// gtile: 64x64, 4 waves (2M x 2K), 4-buf ahead-2, 32KB LDS, vmcnt(8/4/0).
// gt32 : 32x64, 4 waves (2N x 2K), 4-buf ahead-2, 48KB LDS, vmcnt(6/3/0).
// Math identical to R7 (projector fold, diag-exact Q): absmax 0.015625.
// ---------------------------------------------------------------------------

typedef _Float16 f16x8 __attribute__((ext_vector_type(8)));
typedef _Float16 f16x4 __attribute__((ext_vector_type(4)));
typedef float f32x4 __attribute__((ext_vector_type(4)));

enum { EPI_H, EPI_QOFF, EPI_SPLIT, EPI_SOFT, EPI_YP, EPI_ZQ, EPI_ZQFO };

typedef const __attribute__((address_space(1))) void* gas_ptr;
typedef __attribute__((address_space(3))) void* las_ptr;

__device__ __forceinline__ void gload16(const void* g, void* l) {
  __builtin_amdgcn_global_load_lds((gas_ptr)g, (las_ptr)l, 16, 0, 0);
}

__device__ __forceinline__ float softt(float t) {
  float s = fabsf(t) - 1.0f;
  s = s > 0.0f ? s : 0.0f;
  return copysignf(s, t);
}

// ---------------------------------------------------------------------------
// unified conversion kernel (proven). block (32,8).
// z=0..3 transposing f32->f16 (optional scale); z=4 plain f32->f16 x3.
// ---------------------------------------------------------------------------
__global__ __launch_bounds__(256) void convAll(
    const float* __restrict__ e0, const float* __restrict__ e1,
    const float* __restrict__ e2, const float* __restrict__ e3,
    _Float16* __restrict__ o0, _Float16* __restrict__ o1,
    _Float16* __restrict__ o2, _Float16* __restrict__ o3,
    const float* __restrict__ s1, const float* __restrict__ s2,
    const float4* __restrict__ pa, f16x4* __restrict__ qa, int na,
    const float4* __restrict__ pb, f16x4* __restrict__ qb, int nb,
    const float4* __restrict__ pc, f16x4* __restrict__ qc, int nc) {
  const int z = blockIdx.z;
  if (z == 4) {
    const int total = na + nb + nc;
    const int bid = blockIdx.y * 32 + blockIdx.x;
    const int nthr = 2048 * 256;
    for (int i = bid * 256 + threadIdx.y * 32 + threadIdx.x; i < total;
         i += nthr) {
      const float4* s;
      f16x4* d;
      int j = i;
      if (j < na) {
        s = pa; d = qa;
      } else if ((j -= na) < nb) {
        s = pb; d = qb;
      } else {
        j -= nb; s = pc; d = qc;
      }
      float4 v = s[j];
      f16x4 h = {(_Float16)v.x, (_Float16)v.y, (_Float16)v.z, (_Float16)v.w};
      d[j] = h;
    }
    return;
  }
  const float* in = z == 0 ? e0 : z == 1 ? e1 : z == 2 ? e2 : e3;
  _Float16* out = z == 0 ? o0 : z == 1 ? o1 : z == 2 ? o2 : o3;
  const int R = (z < 2) ? 2048 : 1024;
  const int C = 1024;
  const int mode = z == 1 ? 1 : z == 2 ? 2 : 0;
  const float* sv = z == 1 ? s1 : s2;
  __shared__ float t[32][33];
  const int tx = threadIdx.x, ty = threadIdx.y;
  const int c0 = blockIdx.x * 32, r0 = blockIdx.y * 32;
  if (r0 >= R) return;  // uniform per block
#pragma unroll
  for (int i = 0; i < 32; i += 8)
    t[ty + i][tx] = in[(size_t)(r0 + ty + i) * C + c0 + tx];
  __syncthreads();
#pragma unroll
  for (int i = 0; i < 32; i += 8) {
    float v = t[tx][ty + i];
    if (mode == 1) v *= sv[c0 + ty + i];
    if (mode == 2) v *= sv[r0 + tx];
    out[(size_t)(c0 + ty + i) * R + r0 + tx] = (_Float16)v;
  }
}

// ---------------------------------------------------------------------------
// 64x64 tile, NT, 4 waves (wr=M-half, wk=K-half), wave tile 32x64.
// gload_lds 4+4 bufs, ahead 2, vmcnt(8/4/0), 1 barrier/K-step. [R6/R7-proven]
// ---------------------------------------------------------------------------
template <int EPI>
__device__ __forceinline__ void gtile(
    const _Float16* __restrict__ A, int lda, const _Float16* __restrict__ B,
    int ldb, int nK, int N, int brow, int bcol, float* __restrict__ dgout,
    _Float16* __restrict__ oh, _Float16* __restrict__ oh2, _Float16* sm,
    int tid) {
  const int lane = tid & 63;
  const int w = tid >> 6;
  const int wr = w & 1;
  const int wk = w >> 1;
  const int srow = lane >> 3;
  const int scol = ((lane & 7) ^ srow) << 3;
  const int a15 = lane & 15;
  const int hi = lane >> 4;
  const int l7 = lane & 7;

  const _Float16* apg = A + (size_t)(brow + (w << 4) + srow) * lda + scol;
  const _Float16* bpg = B + (size_t)(bcol + (w << 4) + srow) * ldb + scol;
  _Float16* AB = sm;
  _Float16* BB = sm + 16384;
  const int ldstA = w << 10;

  const int ca = ((wk << 2) + hi) ^ l7;
  int raddr[2], baddr[4];
#pragma unroll
  for (int mi = 0; mi < 2; ++mi)
    raddr[mi] = ((wr << 5) + (mi << 4) + a15) * 64 + (ca << 3);
#pragma unroll
  for (int ni = 0; ni < 4; ++ni)
    baddr[ni] = ((ni << 4) + a15) * 64 + (ca << 3);

  f32x4 acc[2][4] = {};

  __syncthreads();

#pragma unroll
  for (int p = 0; p < 2; ++p) {
    gload16(apg + p * 64, AB + p * 4096 + ldstA);
    gload16(apg + p * 64 + (size_t)8 * lda, AB + p * 4096 + ldstA + 512);
    gload16(bpg + p * 64, BB + p * 4096 + ldstA);
    gload16(bpg + p * 64 + (size_t)8 * ldb, BB + p * 4096 + ldstA + 512);
  }

  for (int kt = 0; kt < nK; ++kt) {
    if (kt + 2 < nK) {
      const int bf = (kt + 2) & 3;
      const int co = (kt + 2) << 6;
      gload16(apg + co, AB + bf * 4096 + ldstA);
      gload16(apg + co + (size_t)8 * lda, AB + bf * 4096 + ldstA + 512);
      gload16(bpg + co, BB + bf * 4096 + ldstA);
      gload16(bpg + co + (size_t)8 * ldb, BB + bf * 4096 + ldstA + 512);
    }
    const int rem = nK - 1 - kt;
    if (rem >= 2)
      asm volatile("s_waitcnt vmcnt(8)" ::: "memory");
    else if (rem == 1)
      asm volatile("s_waitcnt vmcnt(4)" ::: "memory");
    else
      asm volatile("s_waitcnt vmcnt(0)" ::: "memory");
    __builtin_amdgcn_s_barrier();
    __builtin_amdgcn_sched_barrier(0);
    const _Float16* Ab = AB + (kt & 3) * 4096;
    const _Float16* Bb = BB + (kt & 3) * 4096;
    f16x8 av[2], bv[4];
    av[0] = *(const f16x8*)(Ab + raddr[0]);
    av[1] = *(const f16x8*)(Ab + raddr[1]);
    bv[0] = *(const f16x8*)(Bb + baddr[0]);
    bv[1] = *(const f16x8*)(Bb + baddr[1]);
    bv[2] = *(const f16x8*)(Bb + baddr[2]);
    bv[3] = *(const f16x8*)(Bb + baddr[3]);
#pragma unroll
    for (int mi = 0; mi < 2; ++mi)
#pragma unroll
      for (int ni = 0; ni < 4; ++ni)
        acc[mi][ni] = __builtin_amdgcn_mfma_f32_16x16x32_f16(
            av[mi], bv[ni], acc[mi][ni], 0, 0, 0);
  }

  __syncthreads();
  float* scr = (float*)sm;
  const int sl = (wr << 6) + lane;
  if (wk == 1) {
#pragma unroll
    for (int mi = 0; mi < 2; ++mi)
#pragma unroll
      for (int ni = 0; ni < 4; ++ni)
#pragma unroll
        for (int r = 0; r < 4; ++r)
          scr[(((mi << 2) + ni) * 4 + r) * 128 + sl] = acc[mi][ni][r];
  }
  __syncthreads();
  if (wk == 0) {
#pragma unroll
    for (int mi = 0; mi < 2; ++mi) {
#pragma unroll
      for (int ni = 0; ni < 4; ++ni) {
#pragma unroll
        for (int r = 0; r < 4; ++r) {
          const float v =
              acc[mi][ni][r] + scr[(((mi << 2) + ni) * 4 + r) * 128 + sl];
          const int row = brow + (wr << 5) + (mi << 4) + (hi << 2) + r;
          const int col = bcol + (ni << 4) + a15;
          const size_t idx = (size_t)row * N + col;
          if constexpr (EPI == EPI_H) {
            oh[idx] = (_Float16)v;
          } else if constexpr (EPI == EPI_QOFF) {
            if (row == col) {
              dgout[row] = 1.0f - v;
              oh[idx] = (_Float16)0.0f;
            } else {
              oh[idx] = (_Float16)(-v);
            }
          } else {  // EPI_SPLIT
            if (col < 1024)
              oh[(size_t)row * 1024 + col] = (_Float16)v;
            else
              oh2[(size_t)row * 1024 + (col - 1024)] = (_Float16)v;
          }
        }
      }
    }
  }
}

// ---------------------------------------------------------------------------
// 32x64 tile, NT, 4 waves (wc=N-half, wk=K-half), wave tile 32x32.
// LDS 48 KB: A 4x4KB + B 4x8KB. 3 gloads/wave/step, ahead 2, vmcnt(6/3/0),
// 1 barrier/K-step. [R7-proven]
// ---------------------------------------------------------------------------
template <int EPI>
__device__ __forceinline__ void gt32(
    const _Float16* __restrict__ A, int lda, const _Float16* __restrict__ B,
    int ldb, int nK, int N, int brow, int bcol, const float* __restrict__ dgv,
    float* __restrict__ fA, float* __restrict__ fB,
    _Float16* __restrict__ oh, const float* __restrict__ fC,
    float* __restrict__ ofin, _Float16* sm, int tid) {
  const int lane = tid & 63;
  const int w = tid >> 6;
  const int wc = w & 1;   // N half (32 cols)
  const int wk = w >> 1;  // K half within 64-step
  const int srow = lane >> 3;
  const int scol = ((lane & 7) ^ srow) << 3;
  const int a15 = lane & 15, hi = lane >> 4, l7 = lane & 7;

  const _Float16* apg = A + (size_t)(brow + (w << 3) + srow) * lda + scol;
  const _Float16* bpg = B + (size_t)(bcol + (w << 4) + srow) * ldb + scol;
  _Float16* AB = sm;          // 4 bufs x 2048 halfs
  _Float16* BB = sm + 8192;   // 4 bufs x 4096 halfs
  const int ca = ((wk << 2) + hi) ^ l7;
  int raddr[2], baddr[2];
#pragma unroll
  for (int mi = 0; mi < 2; ++mi)
    raddr[mi] = ((mi << 4) + a15) * 64 + (ca << 3);
#pragma unroll
  for (int ni = 0; ni < 2; ++ni)
    baddr[ni] = ((wc << 5) + (ni << 4) + a15) * 64 + (ca << 3);

  f32x4 acc[2][2] = {};
  __syncthreads();  // LDS handoff

#pragma unroll
  for (int p = 0; p < 2; ++p) {
    gload16(apg + p * 64, AB + p * 2048 + (w << 9));
    gload16(bpg + p * 64, BB + p * 4096 + (w << 10));
    gload16(bpg + p * 64 + (size_t)8 * ldb, BB + p * 4096 + (w << 10) + 512);
  }
  for (int kt = 0; kt < nK; ++kt) {
    if (kt + 2 < nK) {
      const int bf = (kt + 2) & 3;
      const int co = (kt + 2) << 6;
      gload16(apg + co, AB + bf * 2048 + (w << 9));
      gload16(bpg + co, BB + bf * 4096 + (w << 10));
      gload16(bpg + co + (size_t)8 * ldb, BB + bf * 4096 + (w << 10) + 512);
    }
    const int rem = nK - 1 - kt;
    if (rem >= 2)
      asm volatile("s_waitcnt vmcnt(6)" ::: "memory");
    else if (rem == 1)
      asm volatile("s_waitcnt vmcnt(3)" ::: "memory");
    else
      asm volatile("s_waitcnt vmcnt(0)" ::: "memory");
    __builtin_amdgcn_s_barrier();
    __builtin_amdgcn_sched_barrier(0);
    const _Float16* Ab = AB + (kt & 3) * 2048;
    const _Float16* Bb = BB + (kt & 3) * 4096;
    f16x8 av[2], bv[2];
    av[0] = *(const f16x8*)(Ab + raddr[0]);
    av[1] = *(const f16x8*)(Ab + raddr[1]);
    bv[0] = *(const f16x8*)(Bb + baddr[0]);
    bv[1] = *(const f16x8*)(Bb + baddr[1]);
#pragma unroll
    for (int mi = 0; mi < 2; ++mi)
#pragma unroll
      for (int ni = 0; ni < 2; ++ni)
        acc[mi][ni] = __builtin_amdgcn_mfma_f32_16x16x32_f16(
            av[mi], bv[ni], acc[mi][ni], 0, 0, 0);
  }
  __syncthreads();
  float* scr = (float*)sm;
  const int sl = (wc << 6) + lane;
  if (wk == 1) {
#pragma unroll
    for (int mi = 0; mi < 2; ++mi)
#pragma unroll
      for (int ni = 0; ni < 2; ++ni)
#pragma unroll
        for (int r = 0; r < 4; ++r)
          scr[(((mi << 1) + ni) * 4 + r) * 128 + sl] = acc[mi][ni][r];
  }
  __syncthreads();
  if (wk == 0) {
#pragma unroll
    for (int mi = 0; mi < 2; ++mi) {
#pragma unroll
      for (int ni = 0; ni < 2; ++ni) {
#pragma unroll
        for (int r = 0; r < 4; ++r) {
          const float v =
              acc[mi][ni][r] + scr[(((mi << 1) + ni) * 4 + r) * 128 + sl];
          const int row = brow + (mi << 4) + (hi << 2) + r;
          const int col = bcol + (wc << 5) + (ni << 4) + a15;
          const size_t idx = (size_t)row * N + col;
          if constexpr (EPI == EPI_SOFT) {
            fA[idx] = v;
            float s = softt(v);
            fB[idx] = s;
            oh[idx] = (_Float16)s;
          } else if constexpr (EPI == EPI_YP) {
            ofin[idx] = v;  // ypart = betas2 @ V1^T (f32)
          } else if constexpr (EPI == EPI_ZQ) {
            float t = fA[idx] + dgv[col] * fB[idx] + v;
            float s = softt(t);
            fB[idx] = s;
            oh[idx] = (_Float16)s;
          } else {  // EPI_ZQFO: out = ypart + soft(z0 + dg*z + v)
            float t = fA[idx] + dgv[col] * fB[idx] + v;
            ofin[idx] = fC[idx] + softt(t);
          }
        }
      }
    }
  }
}

// ---------------------------------------------------------------------------
struct WS {
  const _Float16 *ve, *vt1, *w0pT_r, *Bcat, *qoff_r, *x, *kt0s, *vt0T, *w0_r,
      *q_r, *be2;
  _Float16 *w0pT_w, *qoff_w, *w0_w, *q_w, *be2_w, *zhA, *zhB;
  float *z0, *zf, *dg, *yp;
};

// 512-block XCD-chunked map for 16(brow32) x 32(bcol64) tiles
__device__ __forceinline__ void map512(int b, int& br, int& bc) {
  const int x = b & 7, i = b >> 3;
  bc = (x << 2) | (i & 3);  // 0..31
  br = i >> 2;              // 0..15
}

__global__ __launch_bounds__(256, 2) void kD2(WS p) {
  __shared__ __align__(16) _Float16 sm[32768];
  const int tid = threadIdx.x;
  const int bid = blockIdx.x;
  if (bid < 1024) {  // Q = I - Ve Ve^T (2048x2048, K=1024)
    gtile<EPI_QOFF>(p.ve, 1024, p.ve, 1024, 16, 2048, (bid >> 5) << 6,
                    (bid & 31) << 6, p.dg, p.qoff_w, nullptr, sm, tid);
  } else if (bid < 1280) {  // C1: [q|betas2] = x @ Bcat (512x2048, K=2048)
    const int i = bid - 1024;
    gtile<EPI_SPLIT>(p.x, 2048, p.Bcat, 2048, 32, 2048, (i >> 5) << 6,
                     (i & 31) << 6, nullptr, p.q_w, p.be2_w, sm, tid);
  } else {  // W0 = (K0^T s0) @ V0 (1024x1024, K=1024)
    const int i = bid - 1280;
    gtile<EPI_H>(p.kt0s, 1024, p.vt0T, 1024, 16, 1024, (i >> 4) << 6,
                 (i & 15) << 6, nullptr, p.w0_w, nullptr, sm, tid);
  }
}

__global__ __launch_bounds__(256, 2) void kW0p(WS p) {
  __shared__ __align__(16) _Float16 sm[32768];
  const int x = blockIdx.x & 7, i = blockIdx.x >> 3;
  const int bc = (x << 1) | (i & 1), br = i >> 1;  // 16 bcol x 32 brow
  gtile<EPI_H>(p.ve, 1024, p.w0_r, 1024, 16, 1024, br << 6, bc << 6, nullptr,
               p.w0pT_w, nullptr, sm, threadIdx.x);
}

// D4: blocks 0..511 -> z0 = q @ W0' (soft); 512..1023 -> ypart = be2 @ V1^T
__global__ __launch_bounds__(256, 3) void kD4(WS p) {
  __shared__ __align__(16) _Float16 sm[24576];
  const int bid = blockIdx.x;
  int br, bc;
  if (bid < 512) {
    map512(bid, br, bc);
    gt32<EPI_SOFT>(p.q_r, 1024, p.w0pT_r, 1024, 16, 2048, br << 5, bc << 6,
                   nullptr, p.z0, p.zf, p.zhA, nullptr, nullptr, sm,
                   threadIdx.x);
  } else {
    map512(bid - 512, br, bc);
    gt32<EPI_YP>(p.be2, 1024, p.vt1, 1024, 16, 2048, br << 5, bc << 6,
                 nullptr, nullptr, nullptr, nullptr, nullptr, p.yp, sm,
                 threadIdx.x);
  }
}

template <bool AB>
__global__ __launch_bounds__(256, 2) void kZQ(WS p) {
  __shared__ __align__(16) _Float16 sm[24576];
  int br, bc;
  map512(blockIdx.x, br, bc);  // z = soft(z0 + dg*z + z@Qoff)
  gt32<EPI_ZQ>(AB ? p.zhA : p.zhB, 2048, p.qoff_r, 2048, 32, 2048, br << 5,
               bc << 6, p.dg, p.z0, p.zf, AB ? p.zhB : p.zhA, nullptr,
               nullptr, sm, threadIdx.x);
}

__global__ __launch_bounds__(256, 2) void kZQF(WS p, float* out) {
  __shared__ __align__(16) _Float16 sm[24576];
  int br, bc;
  map512(blockIdx.x, br, bc);  // out = ypart + soft(z0 + dg*z + z@Qoff)
  gt32<EPI_ZQFO>(p.zhB, 2048, p.qoff_r, 2048, 32, 2048, br << 5, bc << 6,
                 p.dg, p.z0, p.zf, nullptr, p.yp, out, sm, threadIdx.x);
}

// ---------------------------------------------------------------------------
extern "C" void kernel_launch(void* const* d_in, const int* in_sizes, int n_in,
                              void* d_out, int out_size, void* d_ws,
                              size_t ws_size, hipStream_t stream) {
  const float* x = (const float*)d_in[0];          // (512,2048)
  const float* key_enc = (const float*)d_in[1];    // (2048,1024)
  const float* val_enc = (const float*)d_in[2];    // (2048,1024)
  const float* keys_t0 = (const float*)d_in[3];    // (1024,1024)
  const float* vals_t0 = (const float*)d_in[4];    // (1024,1024)
  const float* scales_t0 = (const float*)d_in[5];  // (1024,)
  const float* keys_t1 = (const float*)d_in[6];    // (2048,1024)
  const float* vals_t1 = (const float*)d_in[7];    // (2048,1024)
  const float* scales_t1 = (const float*)d_in[8];  // (1024,)

  // workspace (half offsets; 1M = 1048576), lifetime-overlaid, ~38 MB
  constexpr size_t M1 = 1048576;
  _Float16* ws = (_Float16*)d_ws;
  _Float16* ve_h = ws;                    // [0,2M)   Ve f16; dead after D3
  float* yp = (float*)ws;                 //   overlay (D4+): ypart f32 (4MB)
  _Float16* vt1_h = ws + 2 * M1;          // [2M,4M)  vals_t1 (D4 ypart B)
  _Float16* w0pT = ws + 4 * M1;           // [4M,6M)  W0' (D3 out, D4 B)
  _Float16* Bcat = ws + 6 * M1;           // [6M,10M) conv out, D2-C1 B
  _Float16* zhA = ws + 6 * M1;            //   overlay post-D2 (1M)
  float* z0_f = (float*)(ws + 7 * M1);    //   overlay post-D2 (2M halfs)
  _Float16* zhB = ws + 9 * M1;            //   overlay post-D2 (1M)
  _Float16* qoff = ws + 10 * M1;          // [10M,14M) Q off-diag (D2 out)
  _Float16* x_h = ws + 14 * M1;           // [14M,15M) conv; D2-C1 A
  _Float16* kt0s = ws + 15 * M1;          // [15M,16M) conv; D2-W0 A
  float* z_f = (float*)(ws + 15 * M1);    //   overlay post-D2 (2M halfs)
  _Float16* vt0T = ws + 16 * M1;          // [16M,17M) conv; D2-W0 B
  _Float16* w0 = ws + 17 * M1;            // [17M,18M) D2-W0 out, D3 B
  _Float16* q_h = ws + 18 * M1;           // [18M,18.5M)
  _Float16* be2 = ws + 18 * M1 + 524288;  // [18.5M,19M)
  float* dg = (float*)(ws + 19 * M1);     // 2048 f32

  WS p;
  p.ve = ve_h; p.vt1 = vt1_h; p.w0pT_r = w0pT; p.w0pT_w = w0pT;
  p.Bcat = Bcat; p.qoff_r = qoff; p.qoff_w = qoff; p.x = x_h;
  p.kt0s = kt0s; p.vt0T = vt0T; p.w0_r = w0; p.w0_w = w0;
  p.q_r = q_h; p.q_w = q_h; p.be2 = be2; p.be2_w = be2;
  p.zhA = zhA; p.zhB = zhB; p.z0 = z0_f; p.zf = z_f; p.dg = dg; p.yp = yp;

  // D1: conversions
  convAll<<<dim3(32, 64, 5), dim3(32, 8), 0, stream>>>(
      key_enc, keys_t1, keys_t0, vals_t0, Bcat, Bcat + 2 * M1, kt0s, vt0T,
      scales_t1, scales_t0, (const float4*)x, (f16x4*)x_h, 262144,
      (const float4*)val_enc, (f16x4*)ve_h, 524288, (const float4*)vals_t1,
      (f16x4*)vt1_h, 524288);
  // D2: Q || C1 || W0
  kD2<<<1536, 256, 0, stream>>>(p);
  // D3: W0' = Ve @ W0^T
  kW0p<<<512, 256, 0, stream>>>(p);
  // D4: z0 = q @ W0' (soft) || ypart = betas2 @ V1^T
  kD4<<<1024, 256, 0, stream>>>(p);
  // D5-D7: ISTA iters 2..4 (zh ping-pong)
  kZQ<true><<<512, 256, 0, stream>>>(p);   // zhA -> zhB
  kZQ<false><<<512, 256, 0, stream>>>(p);  // zhB -> zhA
  kZQ<true><<<512, 256, 0, stream>>>(p);   // zhA -> zhB
  // D8: ISTA iter 5 + out = ypart + soft(...)
  kZQF<<<512, 256, 0, stream>>>(p, (float*)d_out);
}